// Round 11
// baseline (1000.333 us; speedup 1.0000x reference)
//
#include <hip/hip_runtime.h>
#include <hip/hip_bf16.h>

// ---------------------------------------------------------------------------
// VQ-VAE forward. R11: conv2/conv3 back to R9 geometry (TR=6/4, single LDS
// buffer, 3 blocks/CU) + REGISTER prefetch of the next ci-block (global loads
// issued before the tap loop, LDS store between two cheap barriers).
// R10's dbuf regressed conv2 (TR 6->4 cut per-barrier MFMA 33%, occupancy
// 3->2 blocks/CU); decoder dbuf kernels kept (they improved).
//  - conv1 f32 -> fp16 hi/lo NHWC (split once)
//  - conv2/conv3 split-fp16 MFMA (index-exact) + fused bias/relu/2x2 pool
//  - VQ argmax faithful f32; decoder bf16 NHWC MFMA (t2 = 4-parity K2),
//    t4 fused with 1x1 mu conv; fused prep + fused loss kernels.
// ---------------------------------------------------------------------------

#define B_ 256

typedef __attribute__((ext_vector_type(8))) short s16x8;
typedef __attribute__((ext_vector_type(4))) short s16x4;
typedef __attribute__((ext_vector_type(8))) _Float16 f16x8;
typedef __attribute__((ext_vector_type(4))) float f32x4;

__device__ inline ushort f2bf(float f) {
  union { __hip_bfloat16 h; ushort u; } cv;
  cv.h = __float2bfloat16(f);
  return cv.u;
}

// ---------------- fused weight prep (all 6 transforms in one launch) --------
__global__ __launch_bounds__(256) void prep_all(
    const float* __restrict__ t1w, const float* __restrict__ t3w,
    const float* __restrict__ t4w, const float* __restrict__ t2w,
    const float* __restrict__ w2, const float* __restrict__ w3,
    ushort* __restrict__ wp1, ushort* __restrict__ wp3,
    ushort* __restrict__ wp4, ushort* __restrict__ wp2,
    _Float16* __restrict__ w2h, _Float16* __restrict__ w2l,
    _Float16* __restrict__ w3h, _Float16* __restrict__ w3l) {
  const int b = blockIdx.x, t = threadIdx.x;
  if (b < 1024) {
    int idx = b * 256 + t;
    int ci = idx & 127, co = (idx >> 7) & 127, tap = idx >> 14;
    wp1[idx] = f2bf(t1w[((size_t)ci * 128 + co) * 16 + (15 - tap)]);
  } else if (b < 2624) {
    int idx = (b - 1024) * 256 + t;
    int ci = idx & 127, co = (idx >> 7) & 127, tap = idx >> 14;
    wp3[idx] = f2bf(t3w[((size_t)ci * 128 + co) * 25 + (24 - tap)]);
  } else if (b < 4224) {
    int idx = (b - 2624) * 256 + t;
    int ci = idx & 127, co = (idx >> 7) & 127, tap = idx >> 14;
    wp4[idx] = f2bf(t4w[((size_t)ci * 128 + co) * 25 + (24 - tap)]);
  } else if (b < 5248) {
    int idx = (b - 4224) * 256 + t;
    int ci = idx & 127, co = (idx >> 7) & 127;
    int tap = (idx >> 14) & 3, pp = idx >> 16;
    int u = tap >> 1, v = tap & 1, py = pp >> 1, px = pp & 1;
    wp2[idx] = f2bf(
        t2w[(((size_t)ci * 128 + co) * 4 + (py + 2 * u)) * 4 + (px + 2 * v)]);
  } else if (b < 6848) {
    int idx = (b - 5248) * 256 + t;
    int ci = idx & 127, co = (idx >> 7) & 127, tap = idx >> 14;
    float v = w2[((size_t)co * 128 + ci) * 25 + tap];
    _Float16 h = (_Float16)v;
    w2h[idx] = h;
    w2l[idx] = (_Float16)(v - (float)h);
  } else {
    int idx = (b - 6848) * 256 + t;
    int ci = idx & 127, co = (idx >> 7) & 127, tap = idx >> 14;
    float v = w3[((size_t)co * 128 + ci) * 25 + tap];
    _Float16 h = (_Float16)v;
    w3h[idx] = h;
    w3l[idx] = (_Float16)(v - (float)h);
  }
}

// ------- conv1: (B,1,28,28) -> NHWC hi/lo (B,576,128), 5x5, pad0, ReLU ------
__global__ __launch_bounds__(256) void conv1_kernel(
    const float* __restrict__ x, const float* __restrict__ w,
    const float* __restrict__ b, _Float16* __restrict__ oh,
    _Float16* __restrict__ ol) {
  const int n = blockIdx.x;
  __shared__ float xl[784];
  __shared__ float wl[128 * 25];
  __shared__ float bl[128];
  const int t = threadIdx.x;
  for (int e = t; e < 784; e += 256) xl[e] = x[n * 784 + e];
  for (int e = t; e < 3200; e += 256) wl[e] = w[e];
  if (t < 128) bl[t] = b[t];
  __syncthreads();
  const size_t nb = (size_t)n * 73728;
  for (int idx = t; idx < 73728; idx += 256) {
    int co = idx & 127, p = idx >> 7;
    int y = p / 24, xx = p % 24;
    float acc = bl[co];
    const float* wc = &wl[co * 25];
#pragma unroll
    for (int ky = 0; ky < 5; ky++)
#pragma unroll
      for (int kx = 0; kx < 5; kx++)
        acc += xl[(y + ky) * 28 + xx + kx] * wc[ky * 5 + kx];
    float v = fmaxf(acc, 0.f);
    _Float16 h = (_Float16)v;
    oh[nb + idx] = h;
    ol[nb + idx] = (_Float16)(v - (float)h);
  }
}

// ---- split-fp16 MFMA conv + bias(+relu) + 2x2 maxpool, REGISTER prefetch ---
// Single LDS buffer; next ci-block's global loads issued before the tap loop
// (in flight across all taps); store to LDS between two barriers after taps.
template <int IW, int K, int PAD, int TR, bool RELU, bool OUT_F32>
__global__ __launch_bounds__(256, 3) void conv_mfma_pool(
    const _Float16* __restrict__ inh, const _Float16* __restrict__ inl,
    const _Float16* __restrict__ wph, const _Float16* __restrict__ wpl,
    const float* __restrict__ bias, _Float16* __restrict__ outh,
    _Float16* __restrict__ outl, float* __restrict__ outf) {
  constexpr int IH = IW, OW = IW, OH = IW;
  constexpr int PW = IW + 2 * PAD;
  constexpr int SROWS = TR + K - 1;
  constexpr int S = SROWS * PW;
  constexpr int NPOS = TR * OW;
  constexpr int NCH = NPOS / 16;
  constexpr int K2 = K * K;
  constexpr int PITCH = 40;
  constexpr int LIN_ELT = S * PITCH;
  constexpr int LIN_BYTES = 2 * LIN_ELT * 2;  // hi+lo, ONE buffer
  constexpr int SCR_BYTES = 64 * NPOS * 4;
  constexpr int SMEM_BYTES = LIN_BYTES > SCR_BYTES ? LIN_BYTES : SCR_BYTES;
  constexpr int NSTG = (S * 4 + 255) / 256;
  static_assert(NPOS % 16 == 0, "");
  static_assert(TR % 2 == 0 && OW % 2 == 0, "");
  __shared__ __align__(16) char smem[SMEM_BYTES];
  _Float16* linh = (_Float16*)smem;
  _Float16* linl = linh + LIN_ELT;
  const int n = blockIdx.x;
  const int r0 = blockIdx.y * TR;
  const int t = threadIdx.x;
  const int wv = t >> 6;
  const int lane = t & 63;
  const int nn = lane & 15;
  const int q = lane >> 4;
  f32x4 acc0[NCH], acc1[NCH];
#pragma unroll
  for (int c = 0; c < NCH; c++) {
    acc0[c] = f32x4{0.f, 0.f, 0.f, 0.f};
    acc1[c] = f32x4{0.f, 0.f, 0.f, 0.f};
  }
  int base[NCH];
#pragma unroll
  for (int c = 0; c < NCH; c++) {
    int p = c * 16 + nn;
    base[c] = (p / OW) * PW + (p % OW);
  }
  const int rowA = wv * 16 + nn;
  const int rowB = (wv + 4) * 16 + nn;
  f16x8 sh[NSTG], sl[NSTG];

  auto load_stage = [&](int ci0) {
#pragma unroll
    for (int i = 0; i < NSTG; i++) {
      int e = t + i * 256;
      f16x8 vh = {0, 0, 0, 0, 0, 0, 0, 0};
      f16x8 vl = {0, 0, 0, 0, 0, 0, 0, 0};
      if (e < S * 4) {
        int sp = e >> 2, j = e & 3;
        int r = sp / PW, c = sp - r * PW;
        int ir = r0 + r - PAD, ic = c - PAD;
        if (ir >= 0 && ir < IH && ic >= 0 && ic < IW) {
          size_t g = ((size_t)n * (IH * IW) + ir * IW + ic) * 128 + ci0 + j * 8;
          vh = *(const f16x8*)&inh[g];
          vl = *(const f16x8*)&inl[g];
        }
      }
      sh[i] = vh;
      sl[i] = vl;
    }
  };
  auto store_stage = [&]() {
#pragma unroll
    for (int i = 0; i < NSTG; i++) {
      int e = t + i * 256;
      if (e < S * 4) {
        int sp = e >> 2, j = e & 3;
        int st = sp * PITCH + ((j + (sp >> 3)) & 3) * 8;
        *(f16x8*)&linh[st] = sh[i];
        *(f16x8*)&linl[st] = sl[i];
      }
    }
  };

  load_stage(0);
  store_stage();
  __syncthreads();
  for (int cb = 0; cb < 4; cb++) {
    const int ci0 = cb * 32;
    if (cb < 3) load_stage(ci0 + 32);  // in flight across the whole tap loop
    const size_t gA = (size_t)rowA * 128 + ci0 + q * 8;
    const size_t gB = (size_t)rowB * 128 + ci0 + q * 8;
    f16x8 cah0 = *(const f16x8*)&wph[gA];
    f16x8 cal0 = *(const f16x8*)&wpl[gA];
    f16x8 cah1 = *(const f16x8*)&wph[gB];
    f16x8 cal1 = *(const f16x8*)&wpl[gB];
    for (int tap = 0; tap < K2; tap++) {
      f16x8 nah0 = cah0, nal0 = cal0, nah1 = cah1, nal1 = cal1;
      if (tap + 1 < K2) {
        size_t oA = gA + (size_t)(tap + 1) * 16384;
        size_t oB = gB + (size_t)(tap + 1) * 16384;
        nah0 = *(const f16x8*)&wph[oA];
        nal0 = *(const f16x8*)&wpl[oA];
        nah1 = *(const f16x8*)&wph[oB];
        nal1 = *(const f16x8*)&wpl[oB];
      }
      const int ky = tap / K, kx = tap - ky * K;
      const int toff = ky * PW + kx;
#pragma unroll
      for (int c = 0; c < NCH; c++) {
        int s = base[c] + toff;
        int off = s * PITCH + ((q + (s >> 3)) & 3) * 8;
        f16x8 bh = *(const f16x8*)&linh[off];
        f16x8 bl = *(const f16x8*)&linl[off];
        acc0[c] =
            __builtin_amdgcn_mfma_f32_16x16x32_f16(cah0, bh, acc0[c], 0, 0, 0);
        acc0[c] =
            __builtin_amdgcn_mfma_f32_16x16x32_f16(cah0, bl, acc0[c], 0, 0, 0);
        acc0[c] =
            __builtin_amdgcn_mfma_f32_16x16x32_f16(cal0, bh, acc0[c], 0, 0, 0);
        acc1[c] =
            __builtin_amdgcn_mfma_f32_16x16x32_f16(cah1, bh, acc1[c], 0, 0, 0);
        acc1[c] =
            __builtin_amdgcn_mfma_f32_16x16x32_f16(cah1, bl, acc1[c], 0, 0, 0);
        acc1[c] =
            __builtin_amdgcn_mfma_f32_16x16x32_f16(cal1, bh, acc1[c], 0, 0, 0);
      }
      cah0 = nah0; cal0 = nal0; cah1 = nah1; cal1 = nal1;
    }
    if (cb < 3) {
      __syncthreads();   // all waves done reading lin
      store_stage();     // LDS-only gap (loads already complete/waited here)
      __syncthreads();
    }
  }
  // epilogue: scr overlays lin
  __syncthreads();
  float* scr = (float*)smem + wv * 16 * NPOS;
#pragma unroll
  for (int j = 0; j < 2; j++) {
    const int cot = (j ? wv + 4 : wv) * 16;
#pragma unroll
    for (int c = 0; c < NCH; c++) {
      f32x4 a = j ? acc1[c] : acc0[c];
#pragma unroll
      for (int r = 0; r < 4; r++) {
        float v = a[r] + bias[cot + q * 4 + r];
        if (RELU) v = fmaxf(v, 0.f);
        scr[(q * 4 + r) * NPOS + c * 16 + nn] = v;
      }
    }
    __syncthreads();
    for (int e = lane; e < 16 * (TR / 2) * (OW / 2); e += 64) {
      int co_l = e & 15;
      int rem = e >> 4;
      int pr = rem / (OW / 2), pc = rem - pr * (OW / 2);
      const float* s = scr + co_l * NPOS;
      int lp = (2 * pr) * OW + 2 * pc;
      float m =
          fmaxf(fmaxf(s[lp], s[lp + 1]), fmaxf(s[lp + OW], s[lp + OW + 1]));
      int sp_out = (r0 / 2 + pr) * (OW / 2) + pc;
      size_t go =
          ((size_t)n * ((OH / 2) * (OW / 2)) + sp_out) * 128 + cot + co_l;
      if (OUT_F32) {
        outf[go] = m;
      } else {
        _Float16 h = (_Float16)m;
        outh[go] = h;
        outl[go] = (_Float16)(m - (float)h);
      }
    }
    __syncthreads();
  }
}

// ---------------- VQ on NHWC z: argmax(d2) [faithful], gather ---------------
__global__ __launch_bounds__(256) void vq_kernel(
    const float* __restrict__ z, const float* __restrict__ dict,
    float* __restrict__ val, ushort* __restrict__ val_bf,
    float* __restrict__ out_idx) {
  const int n = blockIdx.x;
  __shared__ float zl[36 * 128];
  __shared__ float d2[36 * 129];
  __shared__ float w2n[128];
  __shared__ int bk[36];
  const int t = threadIdx.x;
  const float* zn = z + (size_t)n * 4608;
  for (int e = t; e < 4608; e += 256) zl[e] = zn[e];
  if (t < 128) {
    float s = 0.f;
    const float* wr = dict + t * 128;
    for (int c = 0; c < 128; c++) s += wr[c] * wr[c];
    w2n[t] = s;
  }
  __syncthreads();
  const int k = t & 127, pg = t >> 7;
  float dot[18];
#pragma unroll
  for (int i = 0; i < 18; i++) dot[i] = 0.f;
  const float* wr = dict + k * 128;
  for (int c = 0; c < 128; c++) {
    float wv = wr[c];
#pragma unroll
    for (int i = 0; i < 18; i++) dot[i] += zl[(pg * 18 + i) * 128 + c] * wv;
  }
  float wn = w2n[k];
#pragma unroll
  for (int i = 0; i < 18; i++) d2[(pg * 18 + i) * 129 + k] = wn - 2.f * dot[i];
  __syncthreads();
  if (t < 36) {
    const float* dr = &d2[t * 129];
    float best = dr[0];
    int bi = 0;
    for (int kk = 1; kk < 128; kk++) {
      float v = dr[kk];
      if (v > best) { best = v; bi = kk; }  // strict >: first max (argmax tie)
    }
    bk[t] = bi;
    out_idx[n * 36 + t] = (float)bi;
  }
  __syncthreads();
  float* vn = val + (size_t)n * 4608;
  ushort* vbn = val_bf + (size_t)n * 4608;
  for (int e = t; e < 4608; e += 256) {
    int c = e & 127, p = e >> 7;
    float v = dict[bk[p] * 128 + c];
    vn[e] = v;
    vbn[e] = f2bf(v);
  }
}

// ---- bf16 MFMA deconv (s1), NHWC bf16 io, LDS double-buffer, opt. mu -------
template <int IH, int IW, int OH, int OW, int K, int TR, bool MU_FUSE>
__global__ __launch_bounds__(256, 2) void deconv_mfma(
    const ushort* __restrict__ in, const ushort* __restrict__ wprep,
    const float* __restrict__ bias, const float* __restrict__ mw,
    void* __restrict__ outp) {
  constexpr int PAD = K - 1;
  constexpr int PW = IW + 2 * PAD;
  constexpr int K2 = K * K;
  constexpr int SROWS = TR + K - 1;
  constexpr int S = SROWS * PW;
  constexpr int NPOS = TR * OW;
  constexpr int NCH = (NPOS + 15) / 16;
  constexpr int PITCH = 40;
  constexpr int LIN_ELT = S * PITCH;
  constexpr int NSTG = (S * 4 + 255) / 256;
  __shared__ __align__(16) ushort lin[2][LIN_ELT];
  const int n = blockIdx.x;
  const int r0 = blockIdx.y * TR;
  const int t = threadIdx.x;
  const int wv = t >> 6;
  const int lane = t & 63;
  const int nn = lane & 15;
  const int q = lane >> 4;
  f32x4 acc0[NCH], acc1[NCH];
  int base[NCH];
#pragma unroll
  for (int c = 0; c < NCH; c++) {
    acc0[c] = f32x4{0.f, 0.f, 0.f, 0.f};
    acc1[c] = f32x4{0.f, 0.f, 0.f, 0.f};
    int p = c * 16 + nn;
    int pc = p < NPOS ? p : NPOS - 1;
    base[c] = (pc / OW) * PW + (pc % OW);
  }
  s16x8 stg[NSTG];
  auto load_stage = [&](int ci0) {
#pragma unroll
    for (int i = 0; i < NSTG; i++) {
      int e = t + i * 256;
      s16x8 v = {0, 0, 0, 0, 0, 0, 0, 0};
      if (e < S * 4) {
        int sp = e >> 2, j = e & 3;
        int rr = sp / PW, cc = sp - rr * PW;
        int ir = r0 + rr - PAD, ic = cc - PAD;
        if (ir >= 0 && ir < IH && ic >= 0 && ic < IW)
          v = *(const s16x8*)&in[((size_t)n * (IH * IW) + ir * IW + ic) * 128 +
                                 ci0 + j * 8];
      }
      stg[i] = v;
    }
  };
  auto store_stage = [&](int bsel) {
#pragma unroll
    for (int i = 0; i < NSTG; i++) {
      int e = t + i * 256;
      if (e < S * 4) {
        int sp = e >> 2, j = e & 3;
        *(s16x8*)&lin[bsel][sp * PITCH + ((j + (sp >> 3)) & 3) * 8] = stg[i];
      }
    }
  };

  load_stage(0);
  store_stage(0);
  __syncthreads();
  for (int cb = 0; cb < 4; cb++) {
    const int ci0 = cb * 32;
    if (cb < 3) load_stage(ci0 + 32);
    const ushort* L = lin[cb & 1];
    const size_t gA = (size_t)(wv * 16 + nn) * 128 + ci0 + q * 8;
    const size_t gB = (size_t)((wv + 4) * 16 + nn) * 128 + ci0 + q * 8;
    s16x8 ca0 = *(const s16x8*)&wprep[gA];
    s16x8 ca1 = *(const s16x8*)&wprep[gB];
    for (int tap = 0; tap < K2; tap++) {
      s16x8 na0 = ca0, na1 = ca1;
      if (tap + 1 < K2) {
        na0 = *(const s16x8*)&wprep[gA + (size_t)(tap + 1) * 16384];
        na1 = *(const s16x8*)&wprep[gB + (size_t)(tap + 1) * 16384];
      }
      const int ky = tap / K, kx = tap - ky * K;
      const int toff = ky * PW + kx;
#pragma unroll
      for (int c = 0; c < NCH; c++) {
        int s = base[c] + toff;
        s16x8 b = *(const s16x8*)&L[s * PITCH + ((q + (s >> 3)) & 3) * 8];
        acc0[c] =
            __builtin_amdgcn_mfma_f32_16x16x32_bf16(ca0, b, acc0[c], 0, 0, 0);
        acc1[c] =
            __builtin_amdgcn_mfma_f32_16x16x32_bf16(ca1, b, acc1[c], 0, 0, 0);
      }
      ca0 = na0; ca1 = na1;
    }
    if (cb < 3) {
      store_stage((cb + 1) & 1);
      __syncthreads();
    }
  }
  const int co_a = wv * 16 + q * 4;
  const int co_b = (wv + 4) * 16 + q * 4;
  float ba[4], bb[4];
#pragma unroll
  for (int r = 0; r < 4; r++) {
    ba[r] = bias[co_a + r];
    bb[r] = bias[co_b + r];
  }
  if (!MU_FUSE) {
    ushort* out = (ushort*)outp;
#pragma unroll
    for (int c = 0; c < NCH; c++) {
      int p = c * 16 + nn;
      if (p < NPOS) {
        size_t go = ((size_t)n * (OH * OW) + r0 * OW + p) * 128;
        s16x4 pa, pb;
#pragma unroll
        for (int r = 0; r < 4; r++) {
          pa[r] = (short)f2bf(fmaxf(acc0[c][r] + ba[r], 0.f));
          pb[r] = (short)f2bf(fmaxf(acc1[c][r] + bb[r], 0.f));
        }
        *(s16x4*)&out[go + co_a] = pa;
        *(s16x4*)&out[go + co_b] = pb;
      }
    }
  } else {
    float* out = (float*)outp;
    float wa[4], wb[4];
#pragma unroll
    for (int r = 0; r < 4; r++) {
      wa[r] = mw[co_a + r];
      wb[r] = mw[co_b + r];
    }
#pragma unroll
    for (int c = 0; c < NCH; c++) {
      int p = c * 16 + nn;
      float s = 0.f;
#pragma unroll
      for (int r = 0; r < 4; r++) {
        s += fmaxf(acc0[c][r] + ba[r], 0.f) * wa[r];
        s += fmaxf(acc1[c][r] + bb[r], 0.f) * wb[r];
      }
      s += __shfl_xor(s, 16);
      s += __shfl_xor(s, 32);
      if (q == 0 && p < NPOS)
        atomicAdd(&out[(size_t)n * (OH * OW) + r0 * OW + p], s);
    }
  }
}

// ---------------- t2: k4 s2 deconv via parity decomposition, bf16 NHWC ------
__global__ __launch_bounds__(256, 3) void deconv_s2_mfma(
    const ushort* __restrict__ in, const ushort* __restrict__ wp2,
    const float* __restrict__ bias, ushort* __restrict__ out) {
  constexpr int NCH = 7;
  constexpr int PITCH = 40;
  const int n = blockIdx.x;
  const int pp = blockIdx.y;
  const int py = pp >> 1, px = pp & 1;
  __shared__ __align__(16) ushort lin[121 * PITCH];
  const int t = threadIdx.x;
  const int wv = t >> 6;
  const int lane = t & 63;
  const int nn = lane & 15;
  const int q = lane >> 4;
  f32x4 acc0[NCH], acc1[NCH];
  int base[NCH];
#pragma unroll
  for (int c = 0; c < NCH; c++) {
    acc0[c] = f32x4{0.f, 0.f, 0.f, 0.f};
    acc1[c] = f32x4{0.f, 0.f, 0.f, 0.f};
    int p = c * 16 + nn;
    int pc = p < 100 ? p : 99;
    base[c] = (pc / 10) * 11 + (pc % 10);
  }
  const int toffs[4] = {12, 11, 1, 0};
  for (int cb = 0; cb < 4; cb++) {
    const int ci0 = cb * 32;
    __syncthreads();
    for (int e = t; e < 121 * 4; e += 256) {
      int sp = e >> 2, j = e & 3;
      int r = sp / 11, c2 = sp - r * 11;
      int ir = r - 1, ic = c2 - 1;
      s16x8 v = {0, 0, 0, 0, 0, 0, 0, 0};
      if (ir >= 0 && ir < 9 && ic >= 0 && ic < 9)
        v = *(const s16x8*)&in[((size_t)n * 81 + ir * 9 + ic) * 128 + ci0 +
                               j * 8];
      *(s16x8*)&lin[sp * PITCH + ((j + (sp >> 3)) & 3) * 8] = v;
    }
    __syncthreads();
    const size_t gA =
        ((size_t)(pp * 4) * 128 + wv * 16 + nn) * 128 + ci0 + q * 8;
    const size_t gB =
        ((size_t)(pp * 4) * 128 + (wv + 4) * 16 + nn) * 128 + ci0 + q * 8;
    s16x8 ca0 = *(const s16x8*)&wp2[gA];
    s16x8 ca1 = *(const s16x8*)&wp2[gB];
    for (int tap = 0; tap < 4; tap++) {
      s16x8 na0 = ca0, na1 = ca1;
      if (tap + 1 < 4) {
        na0 = *(const s16x8*)&wp2[gA + (size_t)(tap + 1) * 16384];
        na1 = *(const s16x8*)&wp2[gB + (size_t)(tap + 1) * 16384];
      }
      const int toff = toffs[tap];
#pragma unroll
      for (int c = 0; c < NCH; c++) {
        int s = base[c] + toff;
        s16x8 b = *(const s16x8*)&lin[s * PITCH + ((q + (s >> 3)) & 3) * 8];
        acc0[c] =
            __builtin_amdgcn_mfma_f32_16x16x32_bf16(ca0, b, acc0[c], 0, 0, 0);
        acc1[c] =
            __builtin_amdgcn_mfma_f32_16x16x32_bf16(ca1, b, acc1[c], 0, 0, 0);
      }
      ca0 = na0; ca1 = na1;
    }
  }
  const int co_a = wv * 16 + q * 4;
  const int co_b = (wv + 4) * 16 + q * 4;
#pragma unroll
  for (int c = 0; c < NCH; c++) {
    int p = c * 16 + nn;
    if (p < 100) {
      int oy = 2 * (p / 10) + py, ox = 2 * (p % 10) + px;
      size_t go = ((size_t)n * 400 + oy * 20 + ox) * 128;
      s16x4 pa, pb;
#pragma unroll
      for (int r = 0; r < 4; r++) {
        pa[r] = (short)f2bf(fmaxf(acc0[c][r] + bias[co_a + r], 0.f));
        pb[r] = (short)f2bf(fmaxf(acc1[c][r] + bias[co_b + r], 0.f));
      }
      *(s16x4*)&out[go + co_a] = pa;
      *(s16x4*)&out[go + co_b] = pb;
    }
  }
}

// ---------------- fused losses: rec ([0,784)) + dict/enc ([784,1936)) -------
__global__ __launch_bounds__(256) void loss_kernel(
    const float* __restrict__ mu, const float* __restrict__ mb,
    const float* __restrict__ x, const float4* __restrict__ val4,
    const float4* __restrict__ z4, float* __restrict__ out) {
  const int b = blockIdx.x, t = threadIdx.x;
  __shared__ float red[256];
  if (b < 784) {
    int i = b * 256 + t;
    float d = mu[i] + mb[0] - x[i];
    red[t] = d * d;
  } else {
    int i = (b - 784) * 256 + t;
    float4 a = val4[i], zz = z4[i];
    float dx = a.x - zz.x, dy = a.y - zz.y, dz = a.z - zz.z, dw = a.w - zz.w;
    red[t] = dx * dx + dy * dy + dz * dz + dw * dw;
  }
  __syncthreads();
  for (int off = 128; off > 0; off >>= 1) {
    if (t < off) red[t] += red[t + off];
    __syncthreads();
  }
  if (t == 0) {
    if (b < 784) {
      atomicAdd(out, red[0] * (1.0f / 200704.f));
    } else {
      atomicAdd(out + 1, red[0] * (5.f / 1179648.f));
      atomicAdd(out + 2, red[0] * (1.25f / 1179648.f));
    }
  }
}

// ---------------------------------------------------------------------------
extern "C" void kernel_launch(void* const* d_in, const int* in_sizes, int n_in,
                              void* d_out, int out_size, void* d_ws,
                              size_t ws_size, hipStream_t stream) {
  const float* x = (const float*)d_in[0];
  const float* w1 = (const float*)d_in[1];
  const float* b1 = (const float*)d_in[2];
  const float* w2 = (const float*)d_in[3];
  const float* b2 = (const float*)d_in[4];
  const float* w3 = (const float*)d_in[5];
  const float* b3 = (const float*)d_in[6];
  const float* t1w = (const float*)d_in[7];
  const float* t1b = (const float*)d_in[8];
  const float* t2w = (const float*)d_in[9];
  const float* t2b = (const float*)d_in[10];
  const float* t3w = (const float*)d_in[11];
  const float* t3b = (const float*)d_in[12];
  const float* t4w = (const float*)d_in[13];
  const float* t4b = (const float*)d_in[14];
  const float* mw = (const float*)d_in[15];
  const float* mb = (const float*)d_in[16];
  const float* dictw = (const float*)d_in[17];
  float* out = (float*)d_out;

  float* p = (float*)d_ws;
  _Float16* h1h = (_Float16*)p; p += 9437184;
  _Float16* h1l = (_Float16*)p; p += 9437184;
  _Float16* p1h = (_Float16*)p; p += 2359296;
  _Float16* p1l = (_Float16*)p; p += 2359296;
  float* z = p; p += 1179648;
  float* val = p; p += 1179648;
  ushort* val_bf = (ushort*)p; p += 589824;
  float* mu = p; p += 200704;
  ushort* wp1 = (ushort*)p; p += 131072;
  ushort* wp3 = (ushort*)p; p += 204800;
  ushort* wp4 = (ushort*)p; p += 204800;
  ushort* wp2 = (ushort*)p; p += 131072;
  _Float16* w2h = (_Float16*)p; p += 204800;
  _Float16* w2l = (_Float16*)p; p += 204800;
  _Float16* w3h = (_Float16*)p; p += 204800;
  _Float16* w3l = (_Float16*)p; p += 204800;
  // aliases (dead buffers reused):
  ushort* f1 = (ushort*)p1h;  // (256,81,128) bf16
  ushort* f2 = (ushort*)h1l;  // (256,400,128) bf16
  ushort* f3 = (ushort*)h1h;  // (256,576,128) bf16

  hipMemsetAsync(d_out, 0, 4 * sizeof(float), stream);
  hipMemsetAsync(mu, 0, 200704 * sizeof(float), stream);

  prep_all<<<8448, 256, 0, stream>>>(t1w, t3w, t4w, t2w, w2, w3, wp1, wp3, wp4,
                                     wp2, w2h, w2l, w3h, w3l);

  conv1_kernel<<<B_, 256, 0, stream>>>(x, w1, b1, h1h, h1l);
  // conv2: 24x24 K5 pad2 relu + pool -> p1 hi/lo NHWC (12x12), TR=6, reg-pf
  conv_mfma_pool<24, 5, 2, 6, true, false>
      <<<dim3(B_, 4), 256, 0, stream>>>(h1h, h1l, w2h, w2l, b2, p1h, p1l,
                                        nullptr);
  // conv3: 12x12 K5 pad2 + pool -> z f32 NHWC (6x6), TR=4, reg-pf
  conv_mfma_pool<12, 5, 2, 4, false, true>
      <<<dim3(B_, 3), 256, 0, stream>>>(p1h, p1l, w3h, w3l, b3, nullptr,
                                        nullptr, z);
  vq_kernel<<<B_, 256, 0, stream>>>(z, dictw, val, val_bf, out + 4);
  // t1: 6->9, K4 s1, relu  [bf16 NHWC, dbuf]
  deconv_mfma<6, 6, 9, 9, 4, 9, false>
      <<<dim3(B_, 1), 256, 0, stream>>>(val_bf, wp1, t1b, nullptr, f1);
  // t2: 9->20, K4 s2, relu  [bf16 NHWC, parity decomposition]
  deconv_s2_mfma<<<dim3(B_, 4), 256, 0, stream>>>(f1, wp2, t2b, f2);
  // t3: 20->24, K5 s1, relu  [bf16 NHWC, dbuf]
  deconv_mfma<20, 20, 24, 24, 5, 8, false>
      <<<dim3(B_, 3), 256, 0, stream>>>(f2, wp3, t3b, nullptr, f3);
  // t4: 24->28, K5 s1, relu + fused 1x1 mu  [bf16 NHWC, dbuf]
  deconv_mfma<24, 24, 28, 28, 5, 7, true>
      <<<dim3(B_, 4), 256, 0, stream>>>(f3, wp4, t4b, mw, mu);
  loss_kernel<<<1936, 256, 0, stream>>>(mu, mb, x, (const float4*)val,
                                        (const float4*)z, out);
}

// Round 12
// 954.083 us; speedup vs baseline: 1.0485x; 1.0485x over previous
//
#include <hip/hip_runtime.h>
#include <hip/hip_bf16.h>

// ---------------------------------------------------------------------------
// VQ-VAE forward. R12: conv2/conv3 reverted to the R9 kernel (direct
// global->LDS staging, single buffer, 3 blocks/CU) — R11's register prefetch
// spilled to scratch (FETCH 121->227MB, WRITE 32->181MB) and regressed.
// Decoder keeps R10's LDS double-buffer (measured win). Fused prep + loss.
//  - conv1 f32 -> fp16 hi/lo NHWC (split once)
//  - conv2/conv3 split-fp16 MFMA (index-exact) + fused bias/relu/2x2 pool
//  - VQ argmax faithful f32; decoder bf16 NHWC MFMA (t2 = 4-parity K2),
//    t4 fused with 1x1 mu conv.
// ---------------------------------------------------------------------------

#define B_ 256

typedef __attribute__((ext_vector_type(8))) short s16x8;
typedef __attribute__((ext_vector_type(4))) short s16x4;
typedef __attribute__((ext_vector_type(8))) _Float16 f16x8;
typedef __attribute__((ext_vector_type(4))) float f32x4;

__device__ inline ushort f2bf(float f) {
  union { __hip_bfloat16 h; ushort u; } cv;
  cv.h = __float2bfloat16(f);
  return cv.u;
}

// ---------------- fused weight prep (all 6 transforms in one launch) --------
__global__ __launch_bounds__(256) void prep_all(
    const float* __restrict__ t1w, const float* __restrict__ t3w,
    const float* __restrict__ t4w, const float* __restrict__ t2w,
    const float* __restrict__ w2, const float* __restrict__ w3,
    ushort* __restrict__ wp1, ushort* __restrict__ wp3,
    ushort* __restrict__ wp4, ushort* __restrict__ wp2,
    _Float16* __restrict__ w2h, _Float16* __restrict__ w2l,
    _Float16* __restrict__ w3h, _Float16* __restrict__ w3l) {
  const int b = blockIdx.x, t = threadIdx.x;
  if (b < 1024) {
    int idx = b * 256 + t;
    int ci = idx & 127, co = (idx >> 7) & 127, tap = idx >> 14;
    wp1[idx] = f2bf(t1w[((size_t)ci * 128 + co) * 16 + (15 - tap)]);
  } else if (b < 2624) {
    int idx = (b - 1024) * 256 + t;
    int ci = idx & 127, co = (idx >> 7) & 127, tap = idx >> 14;
    wp3[idx] = f2bf(t3w[((size_t)ci * 128 + co) * 25 + (24 - tap)]);
  } else if (b < 4224) {
    int idx = (b - 2624) * 256 + t;
    int ci = idx & 127, co = (idx >> 7) & 127, tap = idx >> 14;
    wp4[idx] = f2bf(t4w[((size_t)ci * 128 + co) * 25 + (24 - tap)]);
  } else if (b < 5248) {
    int idx = (b - 4224) * 256 + t;
    int ci = idx & 127, co = (idx >> 7) & 127;
    int tap = (idx >> 14) & 3, pp = idx >> 16;
    int u = tap >> 1, v = tap & 1, py = pp >> 1, px = pp & 1;
    wp2[idx] = f2bf(
        t2w[(((size_t)ci * 128 + co) * 4 + (py + 2 * u)) * 4 + (px + 2 * v)]);
  } else if (b < 6848) {
    int idx = (b - 5248) * 256 + t;
    int ci = idx & 127, co = (idx >> 7) & 127, tap = idx >> 14;
    float v = w2[((size_t)co * 128 + ci) * 25 + tap];
    _Float16 h = (_Float16)v;
    w2h[idx] = h;
    w2l[idx] = (_Float16)(v - (float)h);
  } else {
    int idx = (b - 6848) * 256 + t;
    int ci = idx & 127, co = (idx >> 7) & 127, tap = idx >> 14;
    float v = w3[((size_t)co * 128 + ci) * 25 + tap];
    _Float16 h = (_Float16)v;
    w3h[idx] = h;
    w3l[idx] = (_Float16)(v - (float)h);
  }
}

// ------- conv1: (B,1,28,28) -> NHWC hi/lo (B,576,128), 5x5, pad0, ReLU ------
__global__ __launch_bounds__(256) void conv1_kernel(
    const float* __restrict__ x, const float* __restrict__ w,
    const float* __restrict__ b, _Float16* __restrict__ oh,
    _Float16* __restrict__ ol) {
  const int n = blockIdx.x;
  __shared__ float xl[784];
  __shared__ float wl[128 * 25];
  __shared__ float bl[128];
  const int t = threadIdx.x;
  for (int e = t; e < 784; e += 256) xl[e] = x[n * 784 + e];
  for (int e = t; e < 3200; e += 256) wl[e] = w[e];
  if (t < 128) bl[t] = b[t];
  __syncthreads();
  const size_t nb = (size_t)n * 73728;
  for (int idx = t; idx < 73728; idx += 256) {
    int co = idx & 127, p = idx >> 7;
    int y = p / 24, xx = p % 24;
    float acc = bl[co];
    const float* wc = &wl[co * 25];
#pragma unroll
    for (int ky = 0; ky < 5; ky++)
#pragma unroll
      for (int kx = 0; kx < 5; kx++)
        acc += xl[(y + ky) * 28 + xx + kx] * wc[ky * 5 + kx];
    float v = fmaxf(acc, 0.f);
    _Float16 h = (_Float16)v;
    oh[nb + idx] = h;
    ol[nb + idx] = (_Float16)(v - (float)h);
  }
}

// ---------------- split-fp16 MFMA conv + bias(+relu) + 2x2 maxpool ----------
// R9 version: stage directly global->LDS, single buffer, 3 blocks/CU.
template <int IW, int K, int PAD, int TR, bool RELU, bool OUT_F32>
__global__ __launch_bounds__(256, 3) void conv_mfma_pool(
    const _Float16* __restrict__ inh, const _Float16* __restrict__ inl,
    const _Float16* __restrict__ wph, const _Float16* __restrict__ wpl,
    const float* __restrict__ bias, _Float16* __restrict__ outh,
    _Float16* __restrict__ outl, float* __restrict__ outf) {
  constexpr int IH = IW, OW = IW, OH = IW;
  constexpr int PW = IW + 2 * PAD;
  constexpr int SROWS = TR + K - 1;
  constexpr int S = SROWS * PW;
  constexpr int NPOS = TR * OW;
  constexpr int NCH = NPOS / 16;
  constexpr int K2 = K * K;
  constexpr int PITCH = 40;
  constexpr int LIN_ELT = S * PITCH;
  constexpr int LIN_BYTES = 2 * LIN_ELT * 2;
  constexpr int SCR_BYTES = 64 * NPOS * 4;
  constexpr int SMEM_BYTES = LIN_BYTES > SCR_BYTES ? LIN_BYTES : SCR_BYTES;
  static_assert(NPOS % 16 == 0, "");
  static_assert(TR % 2 == 0 && OW % 2 == 0, "");
  __shared__ __align__(16) char smem[SMEM_BYTES];
  _Float16* linh = (_Float16*)smem;
  _Float16* linl = linh + LIN_ELT;
  const int n = blockIdx.x;
  const int r0 = blockIdx.y * TR;
  const int t = threadIdx.x;
  const int wv = t >> 6;
  const int lane = t & 63;
  const int nn = lane & 15;
  const int q = lane >> 4;
  f32x4 acc0[NCH], acc1[NCH];
#pragma unroll
  for (int c = 0; c < NCH; c++) {
    acc0[c] = f32x4{0.f, 0.f, 0.f, 0.f};
    acc1[c] = f32x4{0.f, 0.f, 0.f, 0.f};
  }
  int base[NCH];
#pragma unroll
  for (int c = 0; c < NCH; c++) {
    int p = c * 16 + nn;
    base[c] = (p / OW) * PW + (p % OW);
  }
  const int rowA = wv * 16 + nn;
  const int rowB = (wv + 4) * 16 + nn;
  for (int cb = 0; cb < 4; cb++) {
    const int ci0 = cb * 32;
    __syncthreads();
    for (int e = t; e < S * 4; e += 256) {
      int sp = e >> 2, j = e & 3;
      int r = sp / PW, c = sp - r * PW;
      int ir = r0 + r - PAD, ic = c - PAD;
      f16x8 vh = {0, 0, 0, 0, 0, 0, 0, 0};
      f16x8 vl = {0, 0, 0, 0, 0, 0, 0, 0};
      if (ir >= 0 && ir < IH && ic >= 0 && ic < IW) {
        size_t g = ((size_t)n * (IH * IW) + ir * IW + ic) * 128 + ci0 + j * 8;
        vh = *(const f16x8*)&inh[g];
        vl = *(const f16x8*)&inl[g];
      }
      int st = sp * PITCH + ((j + (sp >> 3)) & 3) * 8;
      *(f16x8*)&linh[st] = vh;
      *(f16x8*)&linl[st] = vl;
    }
    __syncthreads();
    const size_t gA = (size_t)rowA * 128 + ci0 + q * 8;
    const size_t gB = (size_t)rowB * 128 + ci0 + q * 8;
    f16x8 cah0 = *(const f16x8*)&wph[gA];
    f16x8 cal0 = *(const f16x8*)&wpl[gA];
    f16x8 cah1 = *(const f16x8*)&wph[gB];
    f16x8 cal1 = *(const f16x8*)&wpl[gB];
    for (int tap = 0; tap < K2; tap++) {
      f16x8 nah0 = cah0, nal0 = cal0, nah1 = cah1, nal1 = cal1;
      if (tap + 1 < K2) {
        size_t oA = gA + (size_t)(tap + 1) * 16384;
        size_t oB = gB + (size_t)(tap + 1) * 16384;
        nah0 = *(const f16x8*)&wph[oA];
        nal0 = *(const f16x8*)&wpl[oA];
        nah1 = *(const f16x8*)&wph[oB];
        nal1 = *(const f16x8*)&wpl[oB];
      }
      const int ky = tap / K, kx = tap - ky * K;
      const int toff = ky * PW + kx;
#pragma unroll
      for (int c = 0; c < NCH; c++) {
        int s = base[c] + toff;
        int off = s * PITCH + ((q + (s >> 3)) & 3) * 8;
        f16x8 bh = *(const f16x8*)&linh[off];
        f16x8 bl = *(const f16x8*)&linl[off];
        acc0[c] =
            __builtin_amdgcn_mfma_f32_16x16x32_f16(cah0, bh, acc0[c], 0, 0, 0);
        acc0[c] =
            __builtin_amdgcn_mfma_f32_16x16x32_f16(cah0, bl, acc0[c], 0, 0, 0);
        acc0[c] =
            __builtin_amdgcn_mfma_f32_16x16x32_f16(cal0, bh, acc0[c], 0, 0, 0);
        acc1[c] =
            __builtin_amdgcn_mfma_f32_16x16x32_f16(cah1, bh, acc1[c], 0, 0, 0);
        acc1[c] =
            __builtin_amdgcn_mfma_f32_16x16x32_f16(cah1, bl, acc1[c], 0, 0, 0);
        acc1[c] =
            __builtin_amdgcn_mfma_f32_16x16x32_f16(cal1, bh, acc1[c], 0, 0, 0);
      }
      cah0 = nah0; cal0 = nal0; cah1 = nah1; cal1 = nal1;
    }
  }
  // epilogue: bias(+relu) -> per-wave scr (overlays lin) -> 2x2 pool -> NHWC
  __syncthreads();
  float* scr = (float*)smem + wv * 16 * NPOS;
#pragma unroll
  for (int j = 0; j < 2; j++) {
    const int cot = (j ? wv + 4 : wv) * 16;
#pragma unroll
    for (int c = 0; c < NCH; c++) {
      f32x4 a = j ? acc1[c] : acc0[c];
#pragma unroll
      for (int r = 0; r < 4; r++) {
        float v = a[r] + bias[cot + q * 4 + r];
        if (RELU) v = fmaxf(v, 0.f);
        scr[(q * 4 + r) * NPOS + c * 16 + nn] = v;
      }
    }
    __syncthreads();
    for (int e = lane; e < 16 * (TR / 2) * (OW / 2); e += 64) {
      int co_l = e & 15;
      int rem = e >> 4;
      int pr = rem / (OW / 2), pc = rem - pr * (OW / 2);
      const float* s = scr + co_l * NPOS;
      int lp = (2 * pr) * OW + 2 * pc;
      float m =
          fmaxf(fmaxf(s[lp], s[lp + 1]), fmaxf(s[lp + OW], s[lp + OW + 1]));
      int sp_out = (r0 / 2 + pr) * (OW / 2) + pc;
      size_t go =
          ((size_t)n * ((OH / 2) * (OW / 2)) + sp_out) * 128 + cot + co_l;
      if (OUT_F32) {
        outf[go] = m;
      } else {
        _Float16 h = (_Float16)m;
        outh[go] = h;
        outl[go] = (_Float16)(m - (float)h);
      }
    }
    __syncthreads();
  }
}

// ---------------- VQ on NHWC z: argmax(d2) [faithful], gather ---------------
__global__ __launch_bounds__(256) void vq_kernel(
    const float* __restrict__ z, const float* __restrict__ dict,
    float* __restrict__ val, ushort* __restrict__ val_bf,
    float* __restrict__ out_idx) {
  const int n = blockIdx.x;
  __shared__ float zl[36 * 128];
  __shared__ float d2[36 * 129];
  __shared__ float w2n[128];
  __shared__ int bk[36];
  const int t = threadIdx.x;
  const float* zn = z + (size_t)n * 4608;
  for (int e = t; e < 4608; e += 256) zl[e] = zn[e];
  if (t < 128) {
    float s = 0.f;
    const float* wr = dict + t * 128;
    for (int c = 0; c < 128; c++) s += wr[c] * wr[c];
    w2n[t] = s;
  }
  __syncthreads();
  const int k = t & 127, pg = t >> 7;
  float dot[18];
#pragma unroll
  for (int i = 0; i < 18; i++) dot[i] = 0.f;
  const float* wr = dict + k * 128;
  for (int c = 0; c < 128; c++) {
    float wv = wr[c];
#pragma unroll
    for (int i = 0; i < 18; i++) dot[i] += zl[(pg * 18 + i) * 128 + c] * wv;
  }
  float wn = w2n[k];
#pragma unroll
  for (int i = 0; i < 18; i++) d2[(pg * 18 + i) * 129 + k] = wn - 2.f * dot[i];
  __syncthreads();
  if (t < 36) {
    const float* dr = &d2[t * 129];
    float best = dr[0];
    int bi = 0;
    for (int kk = 1; kk < 128; kk++) {
      float v = dr[kk];
      if (v > best) { best = v; bi = kk; }  // strict >: first max (argmax tie)
    }
    bk[t] = bi;
    out_idx[n * 36 + t] = (float)bi;
  }
  __syncthreads();
  float* vn = val + (size_t)n * 4608;
  ushort* vbn = val_bf + (size_t)n * 4608;
  for (int e = t; e < 4608; e += 256) {
    int c = e & 127, p = e >> 7;
    float v = dict[bk[p] * 128 + c];
    vn[e] = v;
    vbn[e] = f2bf(v);
  }
}

// ---- bf16 MFMA deconv (s1), NHWC bf16 io, LDS double-buffer, opt. mu -------
template <int IH, int IW, int OH, int OW, int K, int TR, bool MU_FUSE>
__global__ __launch_bounds__(256, 2) void deconv_mfma(
    const ushort* __restrict__ in, const ushort* __restrict__ wprep,
    const float* __restrict__ bias, const float* __restrict__ mw,
    void* __restrict__ outp) {
  constexpr int PAD = K - 1;
  constexpr int PW = IW + 2 * PAD;
  constexpr int K2 = K * K;
  constexpr int SROWS = TR + K - 1;
  constexpr int S = SROWS * PW;
  constexpr int NPOS = TR * OW;
  constexpr int NCH = (NPOS + 15) / 16;
  constexpr int PITCH = 40;
  constexpr int LIN_ELT = S * PITCH;
  constexpr int NSTG = (S * 4 + 255) / 256;
  __shared__ __align__(16) ushort lin[2][LIN_ELT];
  const int n = blockIdx.x;
  const int r0 = blockIdx.y * TR;
  const int t = threadIdx.x;
  const int wv = t >> 6;
  const int lane = t & 63;
  const int nn = lane & 15;
  const int q = lane >> 4;
  f32x4 acc0[NCH], acc1[NCH];
  int base[NCH];
#pragma unroll
  for (int c = 0; c < NCH; c++) {
    acc0[c] = f32x4{0.f, 0.f, 0.f, 0.f};
    acc1[c] = f32x4{0.f, 0.f, 0.f, 0.f};
    int p = c * 16 + nn;
    int pc = p < NPOS ? p : NPOS - 1;
    base[c] = (pc / OW) * PW + (pc % OW);
  }
  s16x8 stg[NSTG];
  auto load_stage = [&](int ci0) {
#pragma unroll
    for (int i = 0; i < NSTG; i++) {
      int e = t + i * 256;
      s16x8 v = {0, 0, 0, 0, 0, 0, 0, 0};
      if (e < S * 4) {
        int sp = e >> 2, j = e & 3;
        int rr = sp / PW, cc = sp - rr * PW;
        int ir = r0 + rr - PAD, ic = cc - PAD;
        if (ir >= 0 && ir < IH && ic >= 0 && ic < IW)
          v = *(const s16x8*)&in[((size_t)n * (IH * IW) + ir * IW + ic) * 128 +
                                 ci0 + j * 8];
      }
      stg[i] = v;
    }
  };
  auto store_stage = [&](int bsel) {
#pragma unroll
    for (int i = 0; i < NSTG; i++) {
      int e = t + i * 256;
      if (e < S * 4) {
        int sp = e >> 2, j = e & 3;
        *(s16x8*)&lin[bsel][sp * PITCH + ((j + (sp >> 3)) & 3) * 8] = stg[i];
      }
    }
  };

  load_stage(0);
  store_stage(0);
  __syncthreads();
  for (int cb = 0; cb < 4; cb++) {
    const int ci0 = cb * 32;
    if (cb < 3) load_stage(ci0 + 32);
    const ushort* L = lin[cb & 1];
    const size_t gA = (size_t)(wv * 16 + nn) * 128 + ci0 + q * 8;
    const size_t gB = (size_t)((wv + 4) * 16 + nn) * 128 + ci0 + q * 8;
    s16x8 ca0 = *(const s16x8*)&wprep[gA];
    s16x8 ca1 = *(const s16x8*)&wprep[gB];
    for (int tap = 0; tap < K2; tap++) {
      s16x8 na0 = ca0, na1 = ca1;
      if (tap + 1 < K2) {
        na0 = *(const s16x8*)&wprep[gA + (size_t)(tap + 1) * 16384];
        na1 = *(const s16x8*)&wprep[gB + (size_t)(tap + 1) * 16384];
      }
      const int ky = tap / K, kx = tap - ky * K;
      const int toff = ky * PW + kx;
#pragma unroll
      for (int c = 0; c < NCH; c++) {
        int s = base[c] + toff;
        s16x8 b = *(const s16x8*)&L[s * PITCH + ((q + (s >> 3)) & 3) * 8];
        acc0[c] =
            __builtin_amdgcn_mfma_f32_16x16x32_bf16(ca0, b, acc0[c], 0, 0, 0);
        acc1[c] =
            __builtin_amdgcn_mfma_f32_16x16x32_bf16(ca1, b, acc1[c], 0, 0, 0);
      }
      ca0 = na0; ca1 = na1;
    }
    if (cb < 3) {
      store_stage((cb + 1) & 1);
      __syncthreads();
    }
  }
  const int co_a = wv * 16 + q * 4;
  const int co_b = (wv + 4) * 16 + q * 4;
  float ba[4], bb[4];
#pragma unroll
  for (int r = 0; r < 4; r++) {
    ba[r] = bias[co_a + r];
    bb[r] = bias[co_b + r];
  }
  if (!MU_FUSE) {
    ushort* out = (ushort*)outp;
#pragma unroll
    for (int c = 0; c < NCH; c++) {
      int p = c * 16 + nn;
      if (p < NPOS) {
        size_t go = ((size_t)n * (OH * OW) + r0 * OW + p) * 128;
        s16x4 pa, pb;
#pragma unroll
        for (int r = 0; r < 4; r++) {
          pa[r] = (short)f2bf(fmaxf(acc0[c][r] + ba[r], 0.f));
          pb[r] = (short)f2bf(fmaxf(acc1[c][r] + bb[r], 0.f));
        }
        *(s16x4*)&out[go + co_a] = pa;
        *(s16x4*)&out[go + co_b] = pb;
      }
    }
  } else {
    float* out = (float*)outp;
    float wa[4], wb[4];
#pragma unroll
    for (int r = 0; r < 4; r++) {
      wa[r] = mw[co_a + r];
      wb[r] = mw[co_b + r];
    }
#pragma unroll
    for (int c = 0; c < NCH; c++) {
      int p = c * 16 + nn;
      float s = 0.f;
#pragma unroll
      for (int r = 0; r < 4; r++) {
        s += fmaxf(acc0[c][r] + ba[r], 0.f) * wa[r];
        s += fmaxf(acc1[c][r] + bb[r], 0.f) * wb[r];
      }
      s += __shfl_xor(s, 16);
      s += __shfl_xor(s, 32);
      if (q == 0 && p < NPOS)
        atomicAdd(&out[(size_t)n * (OH * OW) + r0 * OW + p], s);
    }
  }
}

// ---------------- t2: k4 s2 deconv via parity decomposition, bf16 NHWC ------
__global__ __launch_bounds__(256, 3) void deconv_s2_mfma(
    const ushort* __restrict__ in, const ushort* __restrict__ wp2,
    const float* __restrict__ bias, ushort* __restrict__ out) {
  constexpr int NCH = 7;
  constexpr int PITCH = 40;
  const int n = blockIdx.x;
  const int pp = blockIdx.y;
  const int py = pp >> 1, px = pp & 1;
  __shared__ __align__(16) ushort lin[121 * PITCH];
  const int t = threadIdx.x;
  const int wv = t >> 6;
  const int lane = t & 63;
  const int nn = lane & 15;
  const int q = lane >> 4;
  f32x4 acc0[NCH], acc1[NCH];
  int base[NCH];
#pragma unroll
  for (int c = 0; c < NCH; c++) {
    acc0[c] = f32x4{0.f, 0.f, 0.f, 0.f};
    acc1[c] = f32x4{0.f, 0.f, 0.f, 0.f};
    int p = c * 16 + nn;
    int pc = p < 100 ? p : 99;
    base[c] = (pc / 10) * 11 + (pc % 10);
  }
  const int toffs[4] = {12, 11, 1, 0};
  for (int cb = 0; cb < 4; cb++) {
    const int ci0 = cb * 32;
    __syncthreads();
    for (int e = t; e < 121 * 4; e += 256) {
      int sp = e >> 2, j = e & 3;
      int r = sp / 11, c2 = sp - r * 11;
      int ir = r - 1, ic = c2 - 1;
      s16x8 v = {0, 0, 0, 0, 0, 0, 0, 0};
      if (ir >= 0 && ir < 9 && ic >= 0 && ic < 9)
        v = *(const s16x8*)&in[((size_t)n * 81 + ir * 9 + ic) * 128 + ci0 +
                               j * 8];
      *(s16x8*)&lin[sp * PITCH + ((j + (sp >> 3)) & 3) * 8] = v;
    }
    __syncthreads();
    const size_t gA =
        ((size_t)(pp * 4) * 128 + wv * 16 + nn) * 128 + ci0 + q * 8;
    const size_t gB =
        ((size_t)(pp * 4) * 128 + (wv + 4) * 16 + nn) * 128 + ci0 + q * 8;
    s16x8 ca0 = *(const s16x8*)&wp2[gA];
    s16x8 ca1 = *(const s16x8*)&wp2[gB];
    for (int tap = 0; tap < 4; tap++) {
      s16x8 na0 = ca0, na1 = ca1;
      if (tap + 1 < 4) {
        na0 = *(const s16x8*)&wp2[gA + (size_t)(tap + 1) * 16384];
        na1 = *(const s16x8*)&wp2[gB + (size_t)(tap + 1) * 16384];
      }
      const int toff = toffs[tap];
#pragma unroll
      for (int c = 0; c < NCH; c++) {
        int s = base[c] + toff;
        s16x8 b = *(const s16x8*)&lin[s * PITCH + ((q + (s >> 3)) & 3) * 8];
        acc0[c] =
            __builtin_amdgcn_mfma_f32_16x16x32_bf16(ca0, b, acc0[c], 0, 0, 0);
        acc1[c] =
            __builtin_amdgcn_mfma_f32_16x16x32_bf16(ca1, b, acc1[c], 0, 0, 0);
      }
      ca0 = na0; ca1 = na1;
    }
  }
  const int co_a = wv * 16 + q * 4;
  const int co_b = (wv + 4) * 16 + q * 4;
#pragma unroll
  for (int c = 0; c < NCH; c++) {
    int p = c * 16 + nn;
    if (p < 100) {
      int oy = 2 * (p / 10) + py, ox = 2 * (p % 10) + px;
      size_t go = ((size_t)n * 400 + oy * 20 + ox) * 128;
      s16x4 pa, pb;
#pragma unroll
      for (int r = 0; r < 4; r++) {
        pa[r] = (short)f2bf(fmaxf(acc0[c][r] + bias[co_a + r], 0.f));
        pb[r] = (short)f2bf(fmaxf(acc1[c][r] + bias[co_b + r], 0.f));
      }
      *(s16x4*)&out[go + co_a] = pa;
      *(s16x4*)&out[go + co_b] = pb;
    }
  }
}

// ---------------- fused losses: rec ([0,784)) + dict/enc ([784,1936)) -------
__global__ __launch_bounds__(256) void loss_kernel(
    const float* __restrict__ mu, const float* __restrict__ mb,
    const float* __restrict__ x, const float4* __restrict__ val4,
    const float4* __restrict__ z4, float* __restrict__ out) {
  const int b = blockIdx.x, t = threadIdx.x;
  __shared__ float red[256];
  if (b < 784) {
    int i = b * 256 + t;
    float d = mu[i] + mb[0] - x[i];
    red[t] = d * d;
  } else {
    int i = (b - 784) * 256 + t;
    float4 a = val4[i], zz = z4[i];
    float dx = a.x - zz.x, dy = a.y - zz.y, dz = a.z - zz.z, dw = a.w - zz.w;
    red[t] = dx * dx + dy * dy + dz * dz + dw * dw;
  }
  __syncthreads();
  for (int off = 128; off > 0; off >>= 1) {
    if (t < off) red[t] += red[t + off];
    __syncthreads();
  }
  if (t == 0) {
    if (b < 784) {
      atomicAdd(out, red[0] * (1.0f / 200704.f));
    } else {
      atomicAdd(out + 1, red[0] * (5.f / 1179648.f));
      atomicAdd(out + 2, red[0] * (1.25f / 1179648.f));
    }
  }
}

// ---------------------------------------------------------------------------
extern "C" void kernel_launch(void* const* d_in, const int* in_sizes, int n_in,
                              void* d_out, int out_size, void* d_ws,
                              size_t ws_size, hipStream_t stream) {
  const float* x = (const float*)d_in[0];
  const float* w1 = (const float*)d_in[1];
  const float* b1 = (const float*)d_in[2];
  const float* w2 = (const float*)d_in[3];
  const float* b2 = (const float*)d_in[4];
  const float* w3 = (const float*)d_in[5];
  const float* b3 = (const float*)d_in[6];
  const float* t1w = (const float*)d_in[7];
  const float* t1b = (const float*)d_in[8];
  const float* t2w = (const float*)d_in[9];
  const float* t2b = (const float*)d_in[10];
  const float* t3w = (const float*)d_in[11];
  const float* t3b = (const float*)d_in[12];
  const float* t4w = (const float*)d_in[13];
  const float* t4b = (const float*)d_in[14];
  const float* mw = (const float*)d_in[15];
  const float* mb = (const float*)d_in[16];
  const float* dictw = (const float*)d_in[17];
  float* out = (float*)d_out;

  float* p = (float*)d_ws;
  _Float16* h1h = (_Float16*)p; p += 9437184;
  _Float16* h1l = (_Float16*)p; p += 9437184;
  _Float16* p1h = (_Float16*)p; p += 2359296;
  _Float16* p1l = (_Float16*)p; p += 2359296;
  float* z = p; p += 1179648;
  float* val = p; p += 1179648;
  ushort* val_bf = (ushort*)p; p += 589824;
  float* mu = p; p += 200704;
  ushort* wp1 = (ushort*)p; p += 131072;
  ushort* wp3 = (ushort*)p; p += 204800;
  ushort* wp4 = (ushort*)p; p += 204800;
  ushort* wp2 = (ushort*)p; p += 131072;
  _Float16* w2h = (_Float16*)p; p += 204800;
  _Float16* w2l = (_Float16*)p; p += 204800;
  _Float16* w3h = (_Float16*)p; p += 204800;
  _Float16* w3l = (_Float16*)p; p += 204800;
  // aliases (dead buffers reused):
  ushort* f1 = (ushort*)p1h;  // (256,81,128) bf16
  ushort* f2 = (ushort*)h1l;  // (256,400,128) bf16
  ushort* f3 = (ushort*)h1h;  // (256,576,128) bf16

  hipMemsetAsync(d_out, 0, 4 * sizeof(float), stream);
  hipMemsetAsync(mu, 0, 200704 * sizeof(float), stream);

  prep_all<<<8448, 256, 0, stream>>>(t1w, t3w, t4w, t2w, w2, w3, wp1, wp3, wp4,
                                     wp2, w2h, w2l, w3h, w3l);

  conv1_kernel<<<B_, 256, 0, stream>>>(x, w1, b1, h1h, h1l);
  // conv2: 24x24 K5 pad2 relu + pool -> p1 hi/lo NHWC (12x12), TR=6 [R9]
  conv_mfma_pool<24, 5, 2, 6, true, false>
      <<<dim3(B_, 4), 256, 0, stream>>>(h1h, h1l, w2h, w2l, b2, p1h, p1l,
                                        nullptr);
  // conv3: 12x12 K5 pad2 + pool -> z f32 NHWC (6x6), TR=4 [R9]
  conv_mfma_pool<12, 5, 2, 4, false, true>
      <<<dim3(B_, 3), 256, 0, stream>>>(p1h, p1l, w3h, w3l, b3, nullptr,
                                        nullptr, z);
  vq_kernel<<<B_, 256, 0, stream>>>(z, dictw, val, val_bf, out + 4);
  // t1: 6->9, K4 s1, relu  [bf16 NHWC, dbuf]
  deconv_mfma<6, 6, 9, 9, 4, 9, false>
      <<<dim3(B_, 1), 256, 0, stream>>>(val_bf, wp1, t1b, nullptr, f1);
  // t2: 9->20, K4 s2, relu  [bf16 NHWC, parity decomposition]
  deconv_s2_mfma<<<dim3(B_, 4), 256, 0, stream>>>(f1, wp2, t2b, f2);
  // t3: 20->24, K5 s1, relu  [bf16 NHWC, dbuf]
  deconv_mfma<20, 20, 24, 24, 5, 8, false>
      <<<dim3(B_, 3), 256, 0, stream>>>(f2, wp3, t3b, nullptr, f3);
  // t4: 24->28, K5 s1, relu + fused 1x1 mu  [bf16 NHWC, dbuf]
  deconv_mfma<24, 24, 28, 28, 5, 7, true>
      <<<dim3(B_, 4), 256, 0, stream>>>(f3, wp4, t4b, mw, mu);
  loss_kernel<<<1936, 256, 0, stream>>>(mu, mb, x, (const float4*)val,
                                        (const float4*)z, out);
}